// Round 5
// baseline (262.909 us; speedup 1.0000x reference)
//
#include <hip/hip_runtime.h>
#include <hip/hip_bf16.h>
#include <stdint.h>

// Problem dims (fixed): B=4, S=2048, IN=1024, OUT=4096 -> M=8192, K=1024, N=4096
#define M_DIM 8192
#define K_DIM 1024
#define N_DIM 4096

typedef __bf16 bf16x8 __attribute__((ext_vector_type(8)));
typedef float  f32x4  __attribute__((ext_vector_type(4)));

__device__ __forceinline__ uint16_t f2bf(float f) {
  union { float f; uint32_t u; } x; x.f = f;
  uint32_t u = x.u;
  return (uint16_t)((u + 0x7FFFu + ((u >> 16) & 1u)) >> 16);  // RNE
}

// ---------------- kernel 1: input fp32 -> bf16 ----------------
__global__ __launch_bounds__(256) void convert_bf16_kernel(
    const float* __restrict__ in, uint16_t* __restrict__ out, int n4) {
  int i = blockIdx.x * 256 + threadIdx.x;
  if (i >= n4) return;
  float4 v = ((const float4*)in)[i];
  ushort4 o;
  o.x = f2bf(v.x); o.y = f2bf(v.y); o.z = f2bf(v.z); o.w = f2bf(v.w);
  ((ushort4*)out)[i] = o;
}

// ---------------- kernel 2: fold everything into W5^T (N x K) bf16 ----------------
// Unchanged from the verified kernel (absmax 0.0156).
__global__ __launch_bounds__(256) void build_w_kernel(
    const float* __restrict__ weight,      // (4096, 1024)
    const float* __restrict__ mask,        // (4096, 1024)
    const float* __restrict__ in_scores,   // (512)
    const float* __restrict__ out_scores,  // (2048)
    const int*   __restrict__ in_mapping,  // (1024)
    const int*   __restrict__ out_mapping, // (4096)
    uint16_t*    __restrict__ w5t)         // (4096, 1024) bf16: row=o, col=i
{
  __shared__ float    w0[K_DIM], w1[K_DIM];
  __shared__ uint16_t o0[K_DIM], o1[K_DIM];

  const int mo = blockIdx.x;       // out-pair [0, 2048)
  const int t  = threadIdx.x;      // [0, 256)

  const int r0 = out_mapping[2 * mo];
  const int r1 = out_mapping[2 * mo + 1];

  ((float4*)w0)[t] = ((const float4*)(weight + (size_t)r0 * K_DIM))[t];
  ((float4*)w1)[t] = ((const float4*)(weight + (size_t)r1 * K_DIM))[t];

  const float ao = out_scores[mo];
  const float so = sinf(ao), co = cosf(ao);

  __syncthreads();

#pragma unroll
  for (int s = 0; s < 2; s++) {
    const int mi = t + s * 256;
    const float ai = in_scores[mi];
    const float si = sinf(ai), ci = cosf(ai);
    const int ia0 = in_mapping[2 * mi];
    const int ia1 = in_mapping[2 * mi + 1];

    const float w00 = w0[ia0], w01 = w0[ia1];
    const float w10 = w1[ia0], w11 = w1[ia1];

    float a00 =  ci * w00 + si * w01;
    float a01 = -si * w00 + ci * w01;
    float a10 =  ci * w10 + si * w11;
    float a11 = -si * w10 + ci * w11;

    float b00 = co * a00 - so * a10;
    float b10 = co * a01 - so * a11;
    float b01 = so * a00 + co * a10;
    float b11 = so * a01 + co * a11;

    const float2 mk0 = *(const float2*)&mask[(size_t)(2 * mo) * K_DIM + 2 * mi];
    const float2 mk1 = *(const float2*)&mask[(size_t)(2 * mo + 1) * K_DIM + 2 * mi];
    b00 *= mk0.x; b10 *= mk0.y;
    b01 *= mk1.x; b11 *= mk1.y;

    float c00 =  co * b00 + so * b01;
    float c10 =  co * b10 + so * b11;
    float c01 = -so * b00 + co * b01;
    float c11 = -so * b10 + co * b11;

    o0[ia0] = f2bf(ci * c00 - si * c10);
    o0[ia1] = f2bf(si * c00 + ci * c10);
    o1[ia0] = f2bf(ci * c01 - si * c11);
    o1[ia1] = f2bf(si * c01 + ci * c11);
  }

  __syncthreads();

  ((uint2*)(w5t + (size_t)r0 * K_DIM))[t] = ((const uint2*)o0)[t];
  ((uint2*)(w5t + (size_t)r1 * K_DIM))[t] = ((const uint2*)o1)[t];
}

// ---------------- kernel 3: GEMM out = A(8192x1024) * W5(1024x4096), bf16 MFMA ----------------
// R9: 2 phases per K-tile (32-MFMA clusters, 4 barriers/tile) — R8's budget
// showed per-tile overhead scales with barrier/phase count (R5 2-sync: ~3000
// overhead cyc; R6-R8 8-sync: ~3700), while a 16-MFMA cluster (621 cyc/SIMD)
// is too short to amortize the ~900-cyc per-phase fixed cost. Same geometry
// (256x256, BK=64, 8 waves 2Mx4N, 2buf x 2half LDS, XOR pre-swizzle, counted
// vmcnt, raw barriers). Reads at phase start (m201-style) keep VGPR ~210
// (acc 128 + af 32 + bfv 32), no cross-phase ping-pong registers.
//   P0: read af(rows 0-63)+bfv; stage A(t+1); bar; lgkm0; 32 MFMA; bar.
//   P1: read af(rows 64-127); stage B(t+2); vmcnt(4); bar; lgkm0; 32 MFMA; bar.
// Ledger @ t P1 (stage-then-wait): B(t+1) 4 + A(t+1) 4 + B(t+2) 4 = 12
// outstanding -> vmcnt(4) drains A(t+1),B(t+1) (>=1 full phase of slack),
// leaves B(t+2) flying. WAR: each buffer's last ds_read drains at a lgkm0
// preceding the end-barrier preceding the overwriting stage (checked for
// As[buf] (read tP1, overwritten t+1 P0), Bs[buf] (read tP0, overwritten
// tP1), prologue, and tails t=14 (vmcnt(0)), t=15 (no stages)).

__device__ __forceinline__ void async_load16(const uint16_t* g, uint16_t* lds_wave_uniform) {
  __builtin_amdgcn_global_load_lds(
      (const __attribute__((address_space(1))) uint32_t*)g,
      (__attribute__((address_space(3))) uint32_t*)lds_wave_uniform,
      16, 0, 0);
}

__global__ __launch_bounds__(512, 2) void gemm_kernel(
    const uint16_t* __restrict__ A,   // (8192, 1024) bf16
    const uint16_t* __restrict__ BT,  // (4096, 1024) bf16 (W5^T, row=n, col=k)
    float* __restrict__ C)            // (8192, 4096) fp32
{
  __shared__ __align__(16) uint16_t As[2][2][128 * 64];  // 2buf x 2half x 16KB
  __shared__ __align__(16) uint16_t Bs[2][2][128 * 64];

  const int tid  = threadIdx.x;     // 0..511
  const int w    = tid >> 6;        // wave 0..7
  const int lane = tid & 63;
  const int quad = lane >> 4;
  const int rr   = lane & 15;
  const int wm   = w >> 2;          // 0..1  (M half of the tile: 128 rows)
  const int wn   = w & 3;           // 0..3  (N quarter: 64 cols)
  const int hA   = wm;              // A half this wave reads
  const int hB   = wn >> 1;         // B half this wave reads

  // XCD-bijective swizzle: 512 blocks, 64 per XCD, bn-fast within XCD.
  const int flat = blockIdx.y * gridDim.x + blockIdx.x;   // 0..511
  const int swz  = ((flat & 7) << 6) | (flat >> 3);
  const int bm   = swz >> 4;        // 0..31  (M tile of 256)
  const int bn   = swz & 15;        // 0..15  (N tile of 256)

  f32x4 acc[8][4] = {};

  // ---- staging source pointers (per-lane, XOR-preswizzled) ----
  const uint16_t* gA[2];
  const uint16_t* gB[2];
#pragma unroll
  for (int ii = 0; ii < 2; ii++) {
    const int c   = ii * 512 + tid;
    const int row = c >> 3;                     // 0..127
    const int g   = (c & 7) ^ (row & 7);
    gA[ii] = A  + (size_t)(bm * 256 + row) * K_DIM + g * 8;
    gB[ii] = BT + (size_t)(bn * 256 + row) * K_DIM + g * 8;
  }

#define STAGE_A(BUF, H, KT)                                                   \
  do {                                                                        \
    _Pragma("unroll")                                                         \
    for (int ii_ = 0; ii_ < 2; ii_++)                                         \
      async_load16(gA[ii_] + (H) * (128 * K_DIM) + (KT) * 64,                 \
                   &As[BUF][H][(ii_ * 512 + w * 64) * 8]);                    \
  } while (0)

#define STAGE_B(BUF, H, KT)                                                   \
  do {                                                                        \
    _Pragma("unroll")                                                         \
    for (int ii_ = 0; ii_ < 2; ii_++)                                         \
      async_load16(gB[ii_] + (H) * (128 * K_DIM) + (KT) * 64,                 \
                   &Bs[BUF][H][(ii_ * 512 + w * 64) * 8]);                    \
  } while (0)

  // ---- fragment LDS offsets (within the wave's half buffer, u16 units) ----
  int offA[8][2], offB[4][2];
#pragma unroll
  for (int i = 0; i < 8; i++) {
    const int r = i * 16 + rr;                  // row within A half
#pragma unroll
    for (int s = 0; s < 2; s++) {
      const int gk = s * 4 + quad;
      offA[i][s] = (r * 8 + (gk ^ (r & 7))) * 8;
    }
  }
#pragma unroll
  for (int j = 0; j < 4; j++) {
    const int r = (wn & 1) * 64 + j * 16 + rr;  // row within B half
#pragma unroll
    for (int s = 0; s < 2; s++) {
      const int gk = s * 4 + quad;
      offB[j][s] = (r * 8 + (gk ^ (r & 7))) * 8;
    }
  }

  // MODE: 0 = steady (t<=13), 1 = t14 (A stage only, vmcnt(0)), 2 = t15 (none)
#define TILE(T, MODE)                                                         \
  {                                                                           \
    const int buf_ = (T) & 1;                                                 \
    const uint16_t* asb_ = &As[buf_][hA][0];                                  \
    const uint16_t* bsb_ = &Bs[buf_][hB][0];                                  \
    bf16x8 af[4][2], bfv[4][2];                                               \
    /* ---- P0: rows 0..63 ---- */                                            \
    _Pragma("unroll") for (int d_ = 0; d_ < 4; d_++)                          \
      _Pragma("unroll") for (int s_ = 0; s_ < 2; s_++)                        \
        af[d_][s_] = *reinterpret_cast<const bf16x8*>(asb_ + offA[d_][s_]);   \
    _Pragma("unroll") for (int j_ = 0; j_ < 4; j_++)                          \
      _Pragma("unroll") for (int s_ = 0; s_ < 2; s_++)                        \
        bfv[j_][s_] = *reinterpret_cast<const bf16x8*>(bsb_ + offB[j_][s_]);  \
    if (MODE < 2) { STAGE_A(buf_ ^ 1, 0, (T) + 1); STAGE_A(buf_ ^ 1, 1, (T) + 1); } \
    __builtin_amdgcn_s_barrier();                                             \
    asm volatile("s_waitcnt lgkmcnt(0)" ::: "memory");                        \
    __builtin_amdgcn_sched_barrier(0);                                        \
    __builtin_amdgcn_s_setprio(1);                                            \
    _Pragma("unroll") for (int s_ = 0; s_ < 2; s_++)                          \
      _Pragma("unroll") for (int d_ = 0; d_ < 4; d_++)                        \
        _Pragma("unroll") for (int j_ = 0; j_ < 4; j_++)                      \
          acc[d_][j_] = __builtin_amdgcn_mfma_f32_16x16x32_bf16(              \
              af[d_][s_], bfv[j_][s_], acc[d_][j_], 0, 0, 0);                 \
    __builtin_amdgcn_s_setprio(0);                                            \
    __builtin_amdgcn_s_barrier();                                             \
    /* ---- P1: rows 64..127 (af regs reused, bfv held) ---- */               \
    _Pragma("unroll") for (int d_ = 0; d_ < 4; d_++)                          \
      _Pragma("unroll") for (int s_ = 0; s_ < 2; s_++)                        \
        af[d_][s_] = *reinterpret_cast<const bf16x8*>(asb_ + offA[4 + d_][s_]); \
    if (MODE == 0) { STAGE_B(buf_, 0, (T) + 2); STAGE_B(buf_, 1, (T) + 2); }  \
    if (MODE == 0)      { asm volatile("s_waitcnt vmcnt(4)" ::: "memory"); }  \
    else if (MODE == 1) { asm volatile("s_waitcnt vmcnt(0)" ::: "memory"); }  \
    __builtin_amdgcn_s_barrier();                                             \
    asm volatile("s_waitcnt lgkmcnt(0)" ::: "memory");                        \
    __builtin_amdgcn_sched_barrier(0);                                        \
    __builtin_amdgcn_s_setprio(1);                                            \
    _Pragma("unroll") for (int s_ = 0; s_ < 2; s_++)                          \
      _Pragma("unroll") for (int d_ = 0; d_ < 4; d_++)                        \
        _Pragma("unroll") for (int j_ = 0; j_ < 4; j_++)                      \
          acc[4 + d_][j_] = __builtin_amdgcn_mfma_f32_16x16x32_bf16(          \
              af[d_][s_], bfv[j_][s_], acc[4 + d_][j_], 0, 0, 0);             \
    __builtin_amdgcn_s_setprio(0);                                            \
    __builtin_amdgcn_s_barrier();                                             \
  }

  // ---- prologue: B(0)->Bs[0], A(0)->As[0], B(1)->Bs[1]; B(1) stays in flight ----
  STAGE_B(0, 0, 0); STAGE_B(0, 1, 0);
  STAGE_A(0, 0, 0); STAGE_A(0, 1, 0);
  STAGE_B(1, 0, 1); STAGE_B(1, 1, 1);
  asm volatile("s_waitcnt vmcnt(4)" ::: "memory");   // B(0), A(0) landed
  __builtin_amdgcn_s_barrier();

  // ---- main loop: 16 K-tiles x 2 phases ----
  for (int t = 0; t < 14; ++t) {
    TILE(t, 0);
  }
  TILE(14, 1);
  TILE(15, 2);

#undef TILE
#undef STAGE_A
#undef STAGE_B

  // ---- epilogue: D layout col = lane&15 (n), row = quad*4 + reg (m) ----
#pragma unroll
  for (int i = 0; i < 8; i++) {
    const int row0 = bm * 256 + wm * 128 + i * 16 + quad * 4;
#pragma unroll
    for (int j = 0; j < 4; j++) {
      const int col = bn * 256 + wn * 64 + j * 16 + rr;
#pragma unroll
      for (int rg = 0; rg < 4; rg++) {
        C[(size_t)(row0 + rg) * N_DIM + col] = acc[i][j][rg];
      }
    }
  }
}

extern "C" void kernel_launch(void* const* d_in, const int* in_sizes, int n_in,
                              void* d_out, int out_size, void* d_ws, size_t ws_size,
                              hipStream_t stream) {
  const float* input      = (const float*)d_in[0];
  const float* weight     = (const float*)d_in[1];
  const float* mask       = (const float*)d_in[2];
  const float* in_scores  = (const float*)d_in[3];
  const float* out_scores = (const float*)d_in[4];
  const int*   in_mapping = (const int*)d_in[5];
  const int*   out_mapping= (const int*)d_in[6];
  // d_in[7] = out_mapping_reverse (folded away), d_in[8] = temperature (unused)
  float* out = (float*)d_out;

  uint16_t* a_bf16 = (uint16_t*)d_ws;                              // 8192*1024 bf16 = 16 MB
  uint16_t* w5t    = (uint16_t*)d_ws + (size_t)M_DIM * K_DIM;      // 4096*1024 bf16 = 8 MB

  convert_bf16_kernel<<<(M_DIM * K_DIM / 4 + 255) / 256, 256, 0, stream>>>(
      input, a_bf16, M_DIM * K_DIM / 4);

  build_w_kernel<<<2048, 256, 0, stream>>>(
      weight, mask, in_scores, out_scores, in_mapping, out_mapping, w5t);

  dim3 grid(N_DIM / 256, M_DIM / 256);  // (16, 32) = 512 blocks, %8 == 0
  gemm_kernel<<<grid, 512, 0, stream>>>(a_bf16, w5t, out);
}

// Round 6
// 254.347 us; speedup vs baseline: 1.0337x; 1.0337x over previous
//
#include <hip/hip_runtime.h>
#include <hip/hip_bf16.h>
#include <stdint.h>

// Problem dims (fixed): B=4, S=2048, IN=1024, OUT=4096 -> M=8192, K=1024, N=4096
#define M_DIM 8192
#define K_DIM 1024
#define N_DIM 4096

typedef __bf16 bf16x8 __attribute__((ext_vector_type(8)));
typedef float  f32x4  __attribute__((ext_vector_type(4)));

__device__ __forceinline__ uint16_t f2bf(float f) {
  union { float f; uint32_t u; } x; x.f = f;
  uint32_t u = x.u;
  return (uint16_t)((u + 0x7FFFu + ((u >> 16) & 1u)) >> 16);  // RNE
}

// ---------------- kernel 1: fused prologue ----------------
// blocks [0, 2048): build W5^T (verified math chain, absmax 0.0156)
// blocks [2048, 10240): input fp32 -> bf16 (2M float4s)
// Independent work; fusing removes one dispatch gap.
__global__ __launch_bounds__(256) void prologue_kernel(
    const float* __restrict__ input,       // (8192, 1024) fp32
    const float* __restrict__ weight,      // (4096, 1024)
    const float* __restrict__ mask,        // (4096, 1024)
    const float* __restrict__ in_scores,   // (512)
    const float* __restrict__ out_scores,  // (2048)
    const int*   __restrict__ in_mapping,  // (1024)
    const int*   __restrict__ out_mapping, // (4096)
    uint16_t*    __restrict__ a_bf16,      // (8192, 1024) bf16
    uint16_t*    __restrict__ w5t)         // (4096, 1024) bf16: row=o, col=i
{
  __shared__ float    w0[K_DIM], w1[K_DIM];
  __shared__ uint16_t o0[K_DIM], o1[K_DIM];

  const int bid = blockIdx.x;
  const int t   = threadIdx.x;

  if (bid >= 2048) {
    // ---- convert part ----
    const int i = (bid - 2048) * 256 + t;     // < 2,097,152 exactly
    float4 v = ((const float4*)input)[i];
    ushort4 o;
    o.x = f2bf(v.x); o.y = f2bf(v.y); o.z = f2bf(v.z); o.w = f2bf(v.w);
    ((ushort4*)a_bf16)[i] = o;
    return;
  }

  // ---- build_w part (unchanged math) ----
  const int mo = bid;              // out-pair [0, 2048)

  const int r0 = out_mapping[2 * mo];
  const int r1 = out_mapping[2 * mo + 1];

  ((float4*)w0)[t] = ((const float4*)(weight + (size_t)r0 * K_DIM))[t];
  ((float4*)w1)[t] = ((const float4*)(weight + (size_t)r1 * K_DIM))[t];

  const float ao = out_scores[mo];
  const float so = sinf(ao), co = cosf(ao);

  __syncthreads();

#pragma unroll
  for (int s = 0; s < 2; s++) {
    const int mi = t + s * 256;
    const float ai = in_scores[mi];
    const float si = sinf(ai), ci = cosf(ai);
    const int ia0 = in_mapping[2 * mi];
    const int ia1 = in_mapping[2 * mi + 1];

    const float w00 = w0[ia0], w01 = w0[ia1];
    const float w10 = w1[ia0], w11 = w1[ia1];

    float a00 =  ci * w00 + si * w01;
    float a01 = -si * w00 + ci * w01;
    float a10 =  ci * w10 + si * w11;
    float a11 = -si * w10 + ci * w11;

    float b00 = co * a00 - so * a10;
    float b10 = co * a01 - so * a11;
    float b01 = so * a00 + co * a10;
    float b11 = so * a01 + co * a11;

    const float2 mk0 = *(const float2*)&mask[(size_t)(2 * mo) * K_DIM + 2 * mi];
    const float2 mk1 = *(const float2*)&mask[(size_t)(2 * mo + 1) * K_DIM + 2 * mi];
    b00 *= mk0.x; b10 *= mk0.y;
    b01 *= mk1.x; b11 *= mk1.y;

    float c00 =  co * b00 + so * b01;
    float c10 =  co * b10 + so * b11;
    float c01 = -so * b00 + co * b01;
    float c11 = -so * b10 + co * b11;

    o0[ia0] = f2bf(ci * c00 - si * c10);
    o0[ia1] = f2bf(si * c00 + ci * c10);
    o1[ia0] = f2bf(ci * c01 - si * c11);
    o1[ia1] = f2bf(si * c01 + ci * c11);
  }

  __syncthreads();

  ((uint2*)(w5t + (size_t)r0 * K_DIM))[t] = ((const uint2*)o0)[t];
  ((uint2*)(w5t + (size_t)r1 * K_DIM))[t] = ((const uint2*)o1)[t];
}

// ---------------- kernel 2: GEMM out = A(8192x1024) * W5(1024x4096), bf16 MFMA ----------------
// R10: occupancy-first redesign from the R4/R8 pipe budget.
//   * wave-tile 128x64 (LDS-read:MFMA pipe ratio 0.9, vs 1.2 at 64x64) in a
//     4-wave block -> tile 256x128, BK=32, 32 K-iters.
//   * LDS = dbuf x (A 256x32 + B 128x32) bf16 = 48 KB -> 2 blocks/CU
//     (VGPR ~205 < 256). Cross-block overlap covers barriers, ds_read drains,
//     and the C-write store-drain (the 1-block/CU 256^2 family's losses).
//   * counted vmcnt: 6 loads/thread/tile; stage(t+2->buf) issued mid-iter
//     after the WAR barrier; vmcnt(6) at iter end drains exactly stage(t+1).
//     Never vmcnt(0) until t=30. Raw s_barrier only.
//   * BK=32 swizzle RE-DERIVED (64 B rows): chunk' = q ^ ((row>>1)&3).
//     Read conflicts: lanes pair only at dRow=8 -> 2-way = free (m136).
//     Old (row&7)-XOR would be 4-way at dRow=4. Applied on BOTH sides
//     (staging source + read offset), rule 21.
__device__ __forceinline__ void async_load16(const uint16_t* g, uint16_t* lds_wave_uniform) {
  __builtin_amdgcn_global_load_lds(
      (const __attribute__((address_space(1))) uint32_t*)g,
      (__attribute__((address_space(3))) uint32_t*)lds_wave_uniform,
      16, 0, 0);
}

__global__ __launch_bounds__(256, 2) void gemm_kernel(
    const uint16_t* __restrict__ A,   // (8192, 1024) bf16
    const uint16_t* __restrict__ BT,  // (4096, 1024) bf16 (W5^T, row=n, col=k)
    float* __restrict__ C)            // (8192, 4096) fp32
{
  __shared__ __align__(16) uint16_t As[2][256 * 32];  // 2 x 16 KB
  __shared__ __align__(16) uint16_t Bs[2][128 * 32];  // 2 x  8 KB

  const int tid  = threadIdx.x;     // 0..255
  const int w    = tid >> 6;        // wave 0..3
  const int lane = tid & 63;
  const int quad = lane >> 4;       // k-chunk of the fragment (k = quad*8..+7)
  const int rr   = lane & 15;
  const int wm2  = w >> 1;          // 0..1 (M half: 128 rows)
  const int wn2  = w & 1;           // 0..1 (N half: 64 cols)

  // XCD-chunked bijective swizzle: 1024 blocks, 128 per XCD, bn fastest.
  const int flat = blockIdx.x;                       // 0..1023
  const int swz  = ((flat & 7) << 7) | (flat >> 3);
  const int bm   = swz >> 5;        // 0..31  (M tile of 256)
  const int bn   = swz & 31;        // 0..31  (N tile of 128)

  f32x4 acc[8][4] = {};

  // ---- staging source pointers (per-lane, XOR-preswizzled, rule 21) ----
  // A tile: 256 rows x 4 chunks(16B) = 1024 chunks / 256 thr = 4 insts.
  // B tile: 128 rows x 4 chunks =  512 chunks -> 2 insts.
  // chunk c: row = c>>2, stored slot q = c&3 holds global chunk g = q ^ ((row>>1)&3).
  const uint16_t* gA[4];
  const uint16_t* gB[2];
#pragma unroll
  for (int ii = 0; ii < 4; ii++) {
    const int c   = ii * 256 + tid;
    const int row = c >> 2;                     // 0..255
    const int g   = (c & 3) ^ ((row >> 1) & 3);
    gA[ii] = A + (size_t)(bm * 256 + row) * K_DIM + g * 8;
  }
#pragma unroll
  for (int ii = 0; ii < 2; ii++) {
    const int c   = ii * 256 + tid;
    const int row = c >> 2;                     // 0..127
    const int g   = (c & 3) ^ ((row >> 1) & 3);
    gB[ii] = BT + (size_t)(bn * 128 + row) * K_DIM + g * 8;
  }

#define STAGE(BUF, KT)                                                        \
  do {                                                                        \
    _Pragma("unroll")                                                         \
    for (int ii_ = 0; ii_ < 4; ii_++)                                         \
      async_load16(gA[ii_] + (KT) * 32, &As[BUF][(ii_ * 256 + w * 64) * 8]);  \
    _Pragma("unroll")                                                         \
    for (int ii_ = 0; ii_ < 2; ii_++)                                         \
      async_load16(gB[ii_] + (KT) * 32, &Bs[BUF][(ii_ * 256 + w * 64) * 8]);  \
  } while (0)

  // ---- fragment LDS offsets (u16 units). 16x16x32 A-frag: row=lane&15,
  // k = quad*8..+7 -> chunk quad, stored at quad ^ ((row>>1)&3). ----
  int offA[8], offB[4];
#pragma unroll
  for (int i = 0; i < 8; i++) {
    const int r = wm2 * 128 + i * 16 + rr;
    offA[i] = (r * 4 + (quad ^ ((r >> 1) & 3))) * 8;
  }
#pragma unroll
  for (int j = 0; j < 4; j++) {
    const int r = wn2 * 64 + j * 16 + rr;
    offB[j] = (r * 4 + (quad ^ ((r >> 1) & 3))) * 8;
  }

  // MODE: 0 steady (t<=29), 1 = t30 (no stage, vmcnt(0)), 2 = t31 (drain)
#define TILE(T, MODE)                                                         \
  {                                                                           \
    const int buf_ = (T) & 1;                                                 \
    const uint16_t* asb_ = &As[buf_][0];                                      \
    const uint16_t* bsb_ = &Bs[buf_][0];                                      \
    bf16x8 af[8], bf[4];                                                      \
    _Pragma("unroll") for (int i_ = 0; i_ < 8; i_++)                          \
      af[i_] = *reinterpret_cast<const bf16x8*>(asb_ + offA[i_]);             \
    _Pragma("unroll") for (int j_ = 0; j_ < 4; j_++)                          \
      bf[j_] = *reinterpret_cast<const bf16x8*>(bsb_ + offB[j_]);             \
    asm volatile("s_waitcnt lgkmcnt(0)" ::: "memory");                        \
    __builtin_amdgcn_sched_barrier(0);  /* rule 18: no MFMA above drain */    \
    __builtin_amdgcn_s_barrier();       /* all waves' reads done (WAR) */     \
    if (MODE == 0) STAGE(buf_, (T) + 2);                                      \
    __builtin_amdgcn_s_setprio(1);                                            \
    _Pragma("unroll") for (int i_ = 0; i_ < 8; i_++)                          \
      _Pragma("unroll") for (int j_ = 0; j_ < 4; j_++)                        \
        acc[i_][j_] = __builtin_amdgcn_mfma_f32_16x16x32_bf16(                \
            af[i_], bf[j_], acc[i_][j_], 0, 0, 0);                            \
    __builtin_amdgcn_s_setprio(0);                                            \
    if (MODE == 0)      { asm volatile("s_waitcnt vmcnt(6)" ::: "memory"); }  \
    else if (MODE == 1) { asm volatile("s_waitcnt vmcnt(0)" ::: "memory"); }  \
    if (MODE < 2) __builtin_amdgcn_s_barrier();                               \
  }

  // ---- prologue: stage tiles 0,1; wait tile 0 (leave tile 1 in flight) ----
  STAGE(0, 0);
  STAGE(1, 1);
  asm volatile("s_waitcnt vmcnt(6)" ::: "memory");
  __builtin_amdgcn_s_barrier();

  // ---- main loop: 32 K-tiles ----
  for (int t = 0; t < 30; ++t) {
    TILE(t, 0);
  }
  TILE(30, 1);
  TILE(31, 2);

#undef TILE
#undef STAGE

  // ---- epilogue: D layout col = lane&15 (n), row = quad*4 + reg (m) ----
  // Overlaps the other resident block's compute (2 blocks/CU).
#pragma unroll
  for (int i = 0; i < 8; i++) {
    const int row0 = bm * 256 + wm2 * 128 + i * 16 + quad * 4;
#pragma unroll
    for (int j = 0; j < 4; j++) {
      const int col = bn * 128 + wn2 * 64 + j * 16 + rr;
#pragma unroll
      for (int rg = 0; rg < 4; rg++) {
        C[(size_t)(row0 + rg) * N_DIM + col] = acc[i][j][rg];
      }
    }
  }
}

extern "C" void kernel_launch(void* const* d_in, const int* in_sizes, int n_in,
                              void* d_out, int out_size, void* d_ws, size_t ws_size,
                              hipStream_t stream) {
  const float* input      = (const float*)d_in[0];
  const float* weight     = (const float*)d_in[1];
  const float* mask       = (const float*)d_in[2];
  const float* in_scores  = (const float*)d_in[3];
  const float* out_scores = (const float*)d_in[4];
  const int*   in_mapping = (const int*)d_in[5];
  const int*   out_mapping= (const int*)d_in[6];
  // d_in[7] = out_mapping_reverse (folded away), d_in[8] = temperature (unused)
  float* out = (float*)d_out;

  uint16_t* a_bf16 = (uint16_t*)d_ws;                              // 8192*1024 bf16 = 16 MB
  uint16_t* w5t    = (uint16_t*)d_ws + (size_t)M_DIM * K_DIM;      // 4096*1024 bf16 = 8 MB

  prologue_kernel<<<10240, 256, 0, stream>>>(
      input, weight, mask, in_scores, out_scores, in_mapping, out_mapping,
      a_bf16, w5t);

  gemm_kernel<<<1024, 256, 0, stream>>>(a_bf16, w5t, out);
}